// Round 6
// baseline (392.101 us; speedup 1.0000x reference)
//
#include <hip/hip_runtime.h>
#include <hip/hip_fp16.h>

// GraphSAGE 3-layer. CSR via two-level counting sort. fp16 feature tables
// (N+1 rows; row N zeroed for branchless gather prefetch). agg stored fp16.
// Layer-2 GEMM fuses the layer-3 per-node dots (t,s); h2 never materialized.
//
// ws: offs | scol | xh h[(N+1)*64] | h1 h[(N+1)*64] | aggh h[N*64] | tarr f[N] | sarr f[N]
//     (sort scratch ebuf/hist/histsc aliases the aggh region)

#define CH 64
#define BKT_SHIFT 9
#define BKT_ROWS 512
#define NBLK 256   // pass A/B blocks; requires nbk <= 256 (N <= 131072)
#define SCAP 12288 // LDS staging capacity in k_build (avg bucket ~8192)

// ---- Pass A: per-block bucket histogram, layout hist[bucket][NBLK] ----
__global__ __launch_bounds__(256) void k_hist(const int* __restrict__ row,
                                              int* __restrict__ hist,
                                              int E, int nbk, int per_blk) {
    __shared__ int h[256];
    int t = threadIdx.x;
    h[t] = 0;
    __syncthreads();
    int s = blockIdx.x * per_blk;
    int e = min(s + per_blk, E);
    for (int i = s + t; i < e; i += 256)
        atomicAdd(&h[row[i] >> BKT_SHIFT], 1);
    __syncthreads();
    if (t < nbk) hist[t * NBLK + blockIdx.x] = h[t];
}

// ---- single-block exclusive scan over M ints (1024 threads) ----
__global__ __launch_bounds__(1024) void k_scan1b(const int* __restrict__ a,
                                                 int* __restrict__ o, int M) {
    __shared__ int wsum[16];
    int t = threadIdx.x;
    int lane = t & 63, w = t >> 6;
    int per = (M + 1023) >> 10;
    int base = t * per;
    int s = 0;
    for (int i = 0; i < per; ++i) {
        int idx = base + i;
        if (idx < M) s += a[idx];
    }
    int v = s;
#pragma unroll
    for (int d = 1; d < 64; d <<= 1) {
        int u = __shfl_up(v, d, 64);
        if (lane >= d) v += u;
    }
    if (lane == 63) wsum[w] = v;
    __syncthreads();
    if (t < 16) {
        int x = wsum[t];
#pragma unroll
        for (int d = 1; d < 16; d <<= 1) {
            int u = __shfl_up(x, d, 16);
            if (t >= d) x += u;
        }
        wsum[t] = x;  // inclusive scan of wave sums
    }
    __syncthreads();
    int run = v - s + (w > 0 ? wsum[w - 1] : 0);
    for (int i = 0; i < per; ++i) {
        int idx = base + i;
        if (idx < M) { o[idx] = run; run += a[idx]; }
    }
}

// ---- Pass B: place packed (rowlocal<<17 | col) into bucket-ordered ebuf ----
__global__ __launch_bounds__(256) void k_binscatter(const int* __restrict__ row,
                                                    const int* __restrict__ col,
                                                    const int* __restrict__ histsc,
                                                    int* __restrict__ ebuf,
                                                    int E, int nbk, int per_blk) {
    __shared__ int cur[256];
    int t = threadIdx.x;
    cur[t] = (t < nbk) ? histsc[t * NBLK + blockIdx.x] : 0;
    __syncthreads();
    int s = blockIdx.x * per_blk;
    int e = min(s + per_blk, E);
    for (int i = s + t; i < e; i += 256) {
        int r = row[i];
        int b = r >> BKT_SHIFT;
        int p = atomicAdd(&cur[b], 1);
        ebuf[p] = ((r & (BKT_ROWS - 1)) << 17) | col[i];
    }
}

// ---- Pass C: per-bucket CSR build; scol staged in LDS, coalesced out ----
__global__ __launch_bounds__(256) void k_build(const int* __restrict__ histsc,
                                               const int* __restrict__ ebuf,
                                               int* __restrict__ offs,
                                               int* __restrict__ scol,
                                               int N, int E, int nbk) {
    __shared__ int cnt[BKT_ROWS];
    __shared__ int loff[BKT_ROWS];
    __shared__ int ts[256];
    __shared__ int sbuf[SCAP];
    int b = blockIdx.x, t = threadIdx.x;
    int g0 = histsc[b * NBLK];
    int g1 = (b + 1 < nbk) ? histsc[(b + 1) * NBLK] : E;
    cnt[t] = 0;
    cnt[t + 256] = 0;
    __syncthreads();
    for (int i = g0 + t; i < g1; i += 256)
        atomicAdd(&cnt[((unsigned)ebuf[i]) >> 17], 1);
    __syncthreads();
    int c0 = cnt[2 * t], c1 = cnt[2 * t + 1];
    ts[t] = c0 + c1;
    __syncthreads();
    for (int off = 1; off < 256; off <<= 1) {
        int v = (t >= off) ? ts[t - off] : 0;
        __syncthreads();
        ts[t] += v;
        __syncthreads();
    }
    int ex = ts[t] - (c0 + c1);
    loff[2 * t] = ex;
    loff[2 * t + 1] = ex + c0;
    __syncthreads();
    int r0 = b << BKT_SHIFT;
    for (int r = t; r < BKT_ROWS; r += 256)
        if (r0 + r < N) offs[r0 + r] = g0 + loff[r];
    if (b == nbk - 1 && t == 0) offs[N] = E;
    cnt[t] = 0;
    cnt[t + 256] = 0;
    __syncthreads();
    int sz = g1 - g0;
    if (sz <= SCAP) {
        for (int i = g0 + t; i < g1; i += 256) {
            unsigned v = (unsigned)ebuf[i];
            int rl = v >> 17;
            int p = atomicAdd(&cnt[rl], 1);
            sbuf[loff[rl] + p] = (int)(v & 0x1FFFFu);
        }
        __syncthreads();
        for (int i = t; i < sz; i += 256) scol[g0 + i] = sbuf[i];
    } else {
        for (int i = g0 + t; i < g1; i += 256) {
            unsigned v = (unsigned)ebuf[i];
            int rl = v >> 17;
            int p = atomicAdd(&cnt[rl], 1);
            scol[g0 + loff[rl] + p] = (int)(v & 0x1FFFFu);
        }
    }
}

// ---- fp32 -> fp16 table; also zeroes dummy row N of xh and h1 ----
__global__ __launch_bounds__(256) void k_tohalf(const float* __restrict__ X,
                                                __half* __restrict__ XH,
                                                __half* __restrict__ H1,
                                                int M, int N) {
    int idx = (blockIdx.x * 256 + threadIdx.x) * 4;
    if (idx < M) {
        float4 v = *(const float4*)(X + idx);
        union { __half2 h[2]; float2 f; } u;
        u.h[0] = __floats2half2_rn(v.x, v.y);
        u.h[1] = __floats2half2_rn(v.z, v.w);
        *(float2*)(XH + idx) = u.f;
    }
    if (blockIdx.x == 0 && threadIdx.x < 16) {
        float4 z = {0.f, 0.f, 0.f, 0.f};
        if (threadIdx.x < 8)
            ((float4*)(XH + (size_t)N * CH))[threadIdx.x] = z;
        else
            ((float4*)(H1 + (size_t)N * CH))[threadIdx.x - 8] = z;
    }
}

// ---- Mean-aggregate: one wave/node, 8 lanes/edge, 4 loads in flight,
//      clamp-to-zero-row prefetch; fp16 output ----
__global__ __launch_bounds__(256) void k_agg(const float4* __restrict__ X4,
                                             const int* __restrict__ offs,
                                             const int* __restrict__ scol,
                                             __half* __restrict__ AGGH, int N, int Em1) {
    int node = blockIdx.x * 4 + (threadIdx.x >> 6);
    int lane = threadIdx.x & 63;
    if (node >= N) return;
    int s = offs[node], e = offs[node + 1];
    int sub = lane & 7;
    int grp = lane >> 3;
    int j = s + grp;
    int i0 = scol[min(j, Em1)];       i0 = (j < e)      ? i0 : N;
    int i1 = scol[min(j + 8, Em1)];   i1 = (j + 8 < e)  ? i1 : N;
    int i2 = scol[min(j + 16, Em1)];  i2 = (j + 16 < e) ? i2 : N;
    int i3 = scol[min(j + 24, Em1)];  i3 = (j + 24 < e) ? i3 : N;
    float4 r0 = X4[(size_t)i0 * 8 + sub];
    float4 r1 = X4[(size_t)i1 * 8 + sub];
    float4 r2 = X4[(size_t)i2 * 8 + sub];
    float4 r3 = X4[(size_t)i3 * 8 + sub];
    float a[8];
#pragma unroll
    for (int k = 0; k < 8; ++k) a[k] = 0.f;
    {
        const __half2* h0 = (const __half2*)&r0;
        const __half2* h1 = (const __half2*)&r1;
        const __half2* h2 = (const __half2*)&r2;
        const __half2* h3 = (const __half2*)&r3;
#pragma unroll
        for (int p = 0; p < 4; ++p) {
            float2 f0 = __half22float2(h0[p]);
            float2 f1 = __half22float2(h1[p]);
            float2 f2 = __half22float2(h2[p]);
            float2 f3 = __half22float2(h3[p]);
            a[2 * p]     += (f0.x + f1.x) + (f2.x + f3.x);
            a[2 * p + 1] += (f0.y + f1.y) + (f2.y + f3.y);
        }
    }
    for (j += 32; j < e; j += 8) {  // rare tail: deg > 32
        float4 r = X4[(size_t)scol[j] * 8 + sub];
        const __half2* h = (const __half2*)&r;
#pragma unroll
        for (int p = 0; p < 4; ++p) {
            float2 f = __half22float2(h[p]);
            a[2 * p]     += f.x;
            a[2 * p + 1] += f.y;
        }
    }
#pragma unroll
    for (int off = 32; off >= 8; off >>= 1)
#pragma unroll
        for (int k = 0; k < 8; ++k)
            a[k] += __shfl_down(a[k], off, 64);
    if (lane < 8) {
        float inv = (e > s) ? 1.0f / (float)(e - s) : 1.0f;
        union { __half2 h[4]; float4 f; } u;
        u.h[0] = __floats2half2_rn(a[0] * inv, a[1] * inv);
        u.h[1] = __floats2half2_rn(a[2] * inv, a[3] * inv);
        u.h[2] = __floats2half2_rn(a[4] * inv, a[5] * inv);
        u.h[3] = __floats2half2_rn(a[6] * inv, a[7] * inv);
        *(float4*)(AGGH + (size_t)node * CH + sub * 8) = u.f;
    }
}

// ---- shared GEMM staging: As[k][n] from fp16 A-table + fp16 AGG ----
__device__ __forceinline__ void gemm_stage(const __half* __restrict__ A,
                                           const __half* __restrict__ AGGH,
                                           const float* __restrict__ W,
                                           float (*As)[68], float (*Ws)[68],
                                           int t, int base, int N) {
    {
        int o = t >> 2;
        int k0 = (t & 3) * 32;
        const float4* wr = (const float4*)(W + o * 128 + k0);
#pragma unroll
        for (int q = 0; q < 8; ++q) {
            float4 v = wr[q];
            Ws[k0 + q * 4 + 0][o] = v.x;
            Ws[k0 + q * 4 + 1][o] = v.y;
            Ws[k0 + q * 4 + 2][o] = v.z;
            Ws[k0 + q * 4 + 3][o] = v.w;
        }
    }
    {
        int n = t >> 2;
        int c0 = (t & 3) * 16;
        int gn = base + n;
        if (gn < N) {
            const float4* xr = (const float4*)(A + (size_t)gn * CH + c0);
            const float4* gr = (const float4*)(AGGH + (size_t)gn * CH + c0);
#pragma unroll
            for (int q = 0; q < 2; ++q) {
                union { float4 f; __half2 h[4]; } u;
                u.f = xr[q];
#pragma unroll
                for (int p = 0; p < 4; ++p) {
                    As[c0 + q * 8 + 2 * p + 0][n] = __low2float(u.h[p]);
                    As[c0 + q * 8 + 2 * p + 1][n] = __high2float(u.h[p]);
                }
                union { float4 f; __half2 h[4]; } g;
                g.f = gr[q];
#pragma unroll
                for (int p = 0; p < 4; ++p) {
                    As[64 + c0 + q * 8 + 2 * p + 0][n] = __low2float(g.h[p]);
                    As[64 + c0 + q * 8 + 2 * p + 1][n] = __high2float(g.h[p]);
                }
            }
        } else {
#pragma unroll
            for (int i = 0; i < 16; ++i) {
                As[c0 + i][n] = 0.f;
                As[64 + c0 + i][n] = 0.f;
            }
        }
    }
}

// ---- layer-1/2 GEMM core producing acc[4][4] ----
#define GEMM_CORE(As, Ws, acc, n0, o0)                                          \
    _Pragma("unroll 4")                                                          \
    for (int k = 0; k < 128; ++k) {                                              \
        float4 a = *(const float4*)&As[k][n0];                                   \
        float4 w = *(const float4*)&Ws[k][o0];                                   \
        acc[0][0] += a.x * w.x; acc[0][1] += a.x * w.y; acc[0][2] += a.x * w.z; acc[0][3] += a.x * w.w; \
        acc[1][0] += a.y * w.x; acc[1][1] += a.y * w.y; acc[1][2] += a.y * w.z; acc[1][3] += a.y * w.w; \
        acc[2][0] += a.z * w.x; acc[2][1] += a.z * w.y; acc[2][2] += a.z * w.z; acc[2][3] += a.z * w.w; \
        acc[3][0] += a.w * w.x; acc[3][1] += a.w * w.y; acc[3][2] += a.w * w.z; acc[3][3] += a.w * w.w; \
    }

// ---- layer-1: h1 = relu(cat(xh,agg).W1^T + b1), fp16 out ----
__global__ __launch_bounds__(256) void k_gemm(const __half* __restrict__ A,
                                              const __half* __restrict__ AGGH,
                                              const float* __restrict__ W,
                                              const float* __restrict__ bias,
                                              __half* __restrict__ OUT, int N) {
    __shared__ float As[128][68];
    __shared__ float Ws[128][68];
    int t = threadIdx.x;
    int base = blockIdx.x * 64;
    gemm_stage(A, AGGH, W, As, Ws, t, base, N);
    __syncthreads();
    int o0 = (t & 15) * 4;
    int n0 = (t >> 4) * 4;
    float acc[4][4];
#pragma unroll
    for (int i = 0; i < 4; ++i)
#pragma unroll
        for (int jj = 0; jj < 4; ++jj) acc[i][jj] = 0.f;
    GEMM_CORE(As, Ws, acc, n0, o0);
    float4 bv = *(const float4*)&bias[o0];
#pragma unroll
    for (int i = 0; i < 4; ++i) {
        int gn = base + n0 + i;
        if (gn < N) {
            float rx = fmaxf(acc[i][0] + bv.x, 0.f);
            float ry = fmaxf(acc[i][1] + bv.y, 0.f);
            float rz = fmaxf(acc[i][2] + bv.z, 0.f);
            float rw = fmaxf(acc[i][3] + bv.w, 0.f);
            union { __half2 h[2]; float2 f; } u;
            u.h[0] = __floats2half2_rn(rx, ry);
            u.h[1] = __floats2half2_rn(rz, rw);
            *(float2*)(OUT + (size_t)gn * CH + o0) = u.f;
        }
    }
}

// ---- layer-2 + layer-3 dots: t[n]=relu(h2).W3[0:64], s[n]=relu(h2).W3[64:128] ----
__global__ __launch_bounds__(256) void k_gemm2(const __half* __restrict__ A,
                                               const __half* __restrict__ AGGH,
                                               const float* __restrict__ W,
                                               const float* __restrict__ bias,
                                               const float* __restrict__ W3,
                                               float* __restrict__ tarr,
                                               float* __restrict__ sarr, int N) {
    __shared__ float As[128][68];
    __shared__ float Ws[128][68];
    int t = threadIdx.x;
    int base = blockIdx.x * 64;
    gemm_stage(A, AGGH, W, As, Ws, t, base, N);
    __syncthreads();
    int o0 = (t & 15) * 4;
    int n0 = (t >> 4) * 4;
    float acc[4][4];
#pragma unroll
    for (int i = 0; i < 4; ++i)
#pragma unroll
        for (int jj = 0; jj < 4; ++jj) acc[i][jj] = 0.f;
    GEMM_CORE(As, Ws, acc, n0, o0);
    float4 bv  = *(const float4*)&bias[o0];
    float4 w3s = *(const float4*)&W3[o0];
    float4 w3a = *(const float4*)&W3[64 + o0];
#pragma unroll
    for (int i = 0; i < 4; ++i) {
        float rx = fmaxf(acc[i][0] + bv.x, 0.f);
        float ry = fmaxf(acc[i][1] + bv.y, 0.f);
        float rz = fmaxf(acc[i][2] + bv.z, 0.f);
        float rw = fmaxf(acc[i][3] + bv.w, 0.f);
        float tp = rx * w3s.x + ry * w3s.y + rz * w3s.z + rw * w3s.w;
        float sp = rx * w3a.x + ry * w3a.y + rz * w3a.z + rw * w3a.w;
#pragma unroll
        for (int off = 8; off >= 1; off >>= 1) {
            tp += __shfl_down(tp, off, 16);
            sp += __shfl_down(sp, off, 16);
        }
        int gn = base + n0 + i;
        if ((t & 15) == 0 && gn < N) {
            tarr[gn] = tp;
            sarr[gn] = sp;
        }
    }
}

// ---- Final: out[n] = t[n] + mean_j s[col_j] + b3 (4B/edge gather) ----
__global__ __launch_bounds__(256) void k_fin(const float* __restrict__ tarr,
                                             const float* __restrict__ sarr,
                                             const int* __restrict__ offs,
                                             const int* __restrict__ scol,
                                             const float* __restrict__ b3,
                                             float* __restrict__ out, int N) {
    int n = blockIdx.x * 256 + threadIdx.x;
    if (n >= N) return;
    int s = offs[n], e = offs[n + 1];
    float s0 = 0.f, s1 = 0.f, s2 = 0.f, s3 = 0.f;
    int j = s;
    for (; j + 4 <= e; j += 4) {
        s0 += sarr[scol[j]];
        s1 += sarr[scol[j + 1]];
        s2 += sarr[scol[j + 2]];
        s3 += sarr[scol[j + 3]];
    }
    for (; j < e; ++j) s0 += sarr[scol[j]];
    float inv = (e > s) ? 1.0f / (float)(e - s) : 1.0f;
    out[n] = tarr[n] + ((s0 + s1) + (s2 + s3)) * inv + b3[0];
}

extern "C" void kernel_launch(void* const* d_in, const int* in_sizes, int n_in,
                              void* d_out, int out_size, void* d_ws, size_t ws_size,
                              hipStream_t stream) {
    const float* x   = (const float*)d_in[0];
    const int* eidx  = (const int*)d_in[1];
    const float* W1  = (const float*)d_in[2];
    const float* b1  = (const float*)d_in[3];
    const float* W2  = (const float*)d_in[4];
    const float* b2  = (const float*)d_in[5];
    const float* W3  = (const float*)d_in[6];
    const float* b3  = (const float*)d_in[7];
    float* out = (float*)d_out;

    const int N = in_sizes[0] / CH;
    const int E = in_sizes[1] / 2;
    const int* row = eidx;
    const int* col = eidx + E;

    int offs_sz = ((N + 1 + 3) / 4) * 4;
    int e_sz    = ((E + 3) / 4) * 4;
    size_t tbl  = (size_t)(N + 1) * CH;  // halves per table (incl. zero row)

    int* offs    = (int*)d_ws;                      // offs_sz ints
    int* scol    = offs + offs_sz;                  // e_sz ints
    __half* xh   = (__half*)(scol + e_sz);          // tbl halves
    __half* h1   = xh + tbl;                        // tbl halves
    __half* aggh = h1 + tbl;                        // N*CH halves
    float* tarr  = (float*)(aggh + (size_t)N * CH); // N floats
    float* sarr  = tarr + N;                        // N floats
    // sort scratch aliases aggh region (dead before aggh's first write)
    int* ebuf   = (int*)aggh;                       // E ints
    int nbk     = (N + BKT_ROWS - 1) >> BKT_SHIFT;
    int* hist   = ebuf + e_sz;                      // nbk*NBLK
    int* histsc = hist + (size_t)nbk * NBLK;        // nbk*NBLK

    int M = nbk * NBLK;
    int per_blk = (E + NBLK - 1) / NBLK;
    int abl = (N + 3) / 4;
    int gbl = (N + 63) / 64;
    int cvb = (N * CH / 4 + 255) / 256;

    // CSR build (4 dispatches)
    k_hist<<<NBLK, 256, 0, stream>>>(row, hist, E, nbk, per_blk);
    k_scan1b<<<1, 1024, 0, stream>>>(hist, histsc, M);
    k_binscatter<<<NBLK, 256, 0, stream>>>(row, col, histsc, ebuf, E, nbk, per_blk);
    k_build<<<nbk, 256, 0, stream>>>(histsc, ebuf, offs, scol, N, E, nbk);

    // x -> fp16 table (+ zero dummy rows of xh, h1)
    k_tohalf<<<cvb, 256, 0, stream>>>(x, xh, h1, N * CH, N);

    // layer 1
    k_agg<<<abl, 256, 0, stream>>>((const float4*)xh, offs, scol, aggh, N, E - 1);
    k_gemm<<<gbl, 256, 0, stream>>>(xh, aggh, W1, b1, h1, N);
    // layer 2 (+ fused layer-3 dots)
    k_agg<<<abl, 256, 0, stream>>>((const float4*)h1, offs, scol, aggh, N, E - 1);
    k_gemm2<<<gbl, 256, 0, stream>>>(h1, aggh, W2, b2, W3, tarr, sarr, N);
    // layer 3 finish
    k_fin<<<(N + 255) / 256, 256, 0, stream>>>(tarr, sarr, offs, scol, b3, out, N);
}

// Round 7
// 313.259 us; speedup vs baseline: 1.2517x; 1.2517x over previous
//
#include <hip/hip_runtime.h>
#include <hip/hip_fp16.h>

// GraphSAGE 3-layer. CSR via two-level counting sort. fp16 feature tables
// (N+1 rows; row N zeroed for branchless gather prefetch). agg stored fp16.
// Layer-2 GEMM fuses the layer-3 per-node dots (t,s); h2 never materialized.
// Scan is the parallel 3-kernel version (R5's single-block scan was a 93 us
// latency chain — reverted).
//
// ws: offs | scol | xh h[(N+1)*64] | h1 h[(N+1)*64] | aggh h[N*64] | tarr f[N] | sarr f[N]
//     (sort scratch ebuf/hist/histsc/part aliases the aggh region)

#define CH 64
#define BKT_SHIFT 9
#define BKT_ROWS 512
#define NBLK 256   // pass A/B blocks; requires nbk <= 256 (N <= 131072)
#define SCAP 12288 // LDS staging capacity in k_build (avg bucket ~8192)

// ---- Pass A: per-block bucket histogram, layout hist[bucket][NBLK] ----
__global__ __launch_bounds__(256) void k_hist(const int* __restrict__ row,
                                              int* __restrict__ hist,
                                              int E, int nbk, int per_blk) {
    __shared__ int h[256];
    int t = threadIdx.x;
    h[t] = 0;
    __syncthreads();
    int s = blockIdx.x * per_blk;
    int e = min(s + per_blk, E);
    for (int i = s + t; i < e; i += 256)
        atomicAdd(&h[row[i] >> BKT_SHIFT], 1);
    __syncthreads();
    if (t < nbk) hist[t * NBLK + blockIdx.x] = h[t];
}

// ---- parallel 3-kernel exclusive scan over M ints ----
__global__ __launch_bounds__(256) void k_ssum(const int* __restrict__ a,
                                              int* __restrict__ part, int M) {
    __shared__ int ts[256];
    int t = threadIdx.x;
    int g0 = blockIdx.x * 1024 + t * 4;
    int s = 0;
#pragma unroll
    for (int i = 0; i < 4; ++i)
        if (g0 + i < M) s += a[g0 + i];
    ts[t] = s;
    __syncthreads();
    for (int off = 128; off >= 1; off >>= 1) {
        if (t < off) ts[t] += ts[t + off];
        __syncthreads();
    }
    if (t == 0) part[blockIdx.x] = ts[0];
}

__global__ void k_sser(int* part, int nb) {
    if (threadIdx.x == 0) {
        int run = 0;
        for (int b = 0; b < nb; ++b) { int v = part[b]; part[b] = run; run += v; }
    }
}

__global__ __launch_bounds__(256) void k_sscan(const int* __restrict__ a,
                                               const int* __restrict__ part,
                                               int* __restrict__ o, int M) {
    __shared__ int ts[256];
    int t = threadIdx.x;
    int g0 = blockIdx.x * 1024 + t * 4;
    int d[4];
    int s = 0;
#pragma unroll
    for (int i = 0; i < 4; ++i) {
        d[i] = (g0 + i < M) ? a[g0 + i] : 0;
        s += d[i];
    }
    ts[t] = s;
    __syncthreads();
    for (int off = 1; off < 256; off <<= 1) {
        int v = (t >= off) ? ts[t - off] : 0;
        __syncthreads();
        ts[t] += v;
        __syncthreads();
    }
    int run = part[blockIdx.x] + ts[t] - s;
#pragma unroll
    for (int i = 0; i < 4; ++i) {
        if (g0 + i < M) o[g0 + i] = run;
        run += d[i];
    }
}

// ---- Pass B: place packed (rowlocal<<17 | col) into bucket-ordered ebuf ----
__global__ __launch_bounds__(256) void k_binscatter(const int* __restrict__ row,
                                                    const int* __restrict__ col,
                                                    const int* __restrict__ histsc,
                                                    int* __restrict__ ebuf,
                                                    int E, int nbk, int per_blk) {
    __shared__ int cur[256];
    int t = threadIdx.x;
    cur[t] = (t < nbk) ? histsc[t * NBLK + blockIdx.x] : 0;
    __syncthreads();
    int s = blockIdx.x * per_blk;
    int e = min(s + per_blk, E);
    for (int i = s + t; i < e; i += 256) {
        int r = row[i];
        int b = r >> BKT_SHIFT;
        int p = atomicAdd(&cur[b], 1);
        ebuf[p] = ((r & (BKT_ROWS - 1)) << 17) | col[i];
    }
}

// ---- Pass C: per-bucket CSR build; scol staged in LDS, coalesced out ----
__global__ __launch_bounds__(256) void k_build(const int* __restrict__ histsc,
                                               const int* __restrict__ ebuf,
                                               int* __restrict__ offs,
                                               int* __restrict__ scol,
                                               int N, int E, int nbk) {
    __shared__ int cnt[BKT_ROWS];
    __shared__ int loff[BKT_ROWS];
    __shared__ int ts[256];
    __shared__ int sbuf[SCAP];
    int b = blockIdx.x, t = threadIdx.x;
    int g0 = histsc[b * NBLK];
    int g1 = (b + 1 < nbk) ? histsc[(b + 1) * NBLK] : E;
    cnt[t] = 0;
    cnt[t + 256] = 0;
    __syncthreads();
    for (int i = g0 + t; i < g1; i += 256)
        atomicAdd(&cnt[((unsigned)ebuf[i]) >> 17], 1);
    __syncthreads();
    int c0 = cnt[2 * t], c1 = cnt[2 * t + 1];
    ts[t] = c0 + c1;
    __syncthreads();
    for (int off = 1; off < 256; off <<= 1) {
        int v = (t >= off) ? ts[t - off] : 0;
        __syncthreads();
        ts[t] += v;
        __syncthreads();
    }
    int ex = ts[t] - (c0 + c1);
    loff[2 * t] = ex;
    loff[2 * t + 1] = ex + c0;
    __syncthreads();
    int r0 = b << BKT_SHIFT;
    for (int r = t; r < BKT_ROWS; r += 256)
        if (r0 + r < N) offs[r0 + r] = g0 + loff[r];
    if (b == nbk - 1 && t == 0) offs[N] = E;
    cnt[t] = 0;
    cnt[t + 256] = 0;
    __syncthreads();
    int sz = g1 - g0;
    if (sz <= SCAP) {
        for (int i = g0 + t; i < g1; i += 256) {
            unsigned v = (unsigned)ebuf[i];
            int rl = v >> 17;
            int p = atomicAdd(&cnt[rl], 1);
            sbuf[loff[rl] + p] = (int)(v & 0x1FFFFu);
        }
        __syncthreads();
        for (int i = t; i < sz; i += 256) scol[g0 + i] = sbuf[i];
    } else {
        for (int i = g0 + t; i < g1; i += 256) {
            unsigned v = (unsigned)ebuf[i];
            int rl = v >> 17;
            int p = atomicAdd(&cnt[rl], 1);
            scol[g0 + loff[rl] + p] = (int)(v & 0x1FFFFu);
        }
    }
}

// ---- fp32 -> fp16 table; also zeroes dummy row N of xh and h1 ----
__global__ __launch_bounds__(256) void k_tohalf(const float* __restrict__ X,
                                                __half* __restrict__ XH,
                                                __half* __restrict__ H1,
                                                int M, int N) {
    int idx = (blockIdx.x * 256 + threadIdx.x) * 4;
    if (idx < M) {
        float4 v = *(const float4*)(X + idx);
        union { __half2 h[2]; float2 f; } u;
        u.h[0] = __floats2half2_rn(v.x, v.y);
        u.h[1] = __floats2half2_rn(v.z, v.w);
        *(float2*)(XH + idx) = u.f;
    }
    if (blockIdx.x == 0 && threadIdx.x < 16) {
        float4 z = {0.f, 0.f, 0.f, 0.f};
        if (threadIdx.x < 8)
            ((float4*)(XH + (size_t)N * CH))[threadIdx.x] = z;
        else
            ((float4*)(H1 + (size_t)N * CH))[threadIdx.x - 8] = z;
    }
}

// ---- Mean-aggregate: one wave/node, 8 lanes/edge, 4 loads in flight,
//      clamp-to-zero-row prefetch; fp16 output ----
__global__ __launch_bounds__(256) void k_agg(const float4* __restrict__ X4,
                                             const int* __restrict__ offs,
                                             const int* __restrict__ scol,
                                             __half* __restrict__ AGGH, int N, int Em1) {
    int node = blockIdx.x * 4 + (threadIdx.x >> 6);
    int lane = threadIdx.x & 63;
    if (node >= N) return;
    int s = offs[node], e = offs[node + 1];
    int sub = lane & 7;
    int grp = lane >> 3;
    int j = s + grp;
    int i0 = scol[min(j, Em1)];       i0 = (j < e)      ? i0 : N;
    int i1 = scol[min(j + 8, Em1)];   i1 = (j + 8 < e)  ? i1 : N;
    int i2 = scol[min(j + 16, Em1)];  i2 = (j + 16 < e) ? i2 : N;
    int i3 = scol[min(j + 24, Em1)];  i3 = (j + 24 < e) ? i3 : N;
    float4 r0 = X4[(size_t)i0 * 8 + sub];
    float4 r1 = X4[(size_t)i1 * 8 + sub];
    float4 r2 = X4[(size_t)i2 * 8 + sub];
    float4 r3 = X4[(size_t)i3 * 8 + sub];
    float a[8];
#pragma unroll
    for (int k = 0; k < 8; ++k) a[k] = 0.f;
    {
        const __half2* h0 = (const __half2*)&r0;
        const __half2* h1 = (const __half2*)&r1;
        const __half2* h2 = (const __half2*)&r2;
        const __half2* h3 = (const __half2*)&r3;
#pragma unroll
        for (int p = 0; p < 4; ++p) {
            float2 f0 = __half22float2(h0[p]);
            float2 f1 = __half22float2(h1[p]);
            float2 f2 = __half22float2(h2[p]);
            float2 f3 = __half22float2(h3[p]);
            a[2 * p]     += (f0.x + f1.x) + (f2.x + f3.x);
            a[2 * p + 1] += (f0.y + f1.y) + (f2.y + f3.y);
        }
    }
    for (j += 32; j < e; j += 8) {  // rare tail: deg > 32
        float4 r = X4[(size_t)scol[j] * 8 + sub];
        const __half2* h = (const __half2*)&r;
#pragma unroll
        for (int p = 0; p < 4; ++p) {
            float2 f = __half22float2(h[p]);
            a[2 * p]     += f.x;
            a[2 * p + 1] += f.y;
        }
    }
#pragma unroll
    for (int off = 32; off >= 8; off >>= 1)
#pragma unroll
        for (int k = 0; k < 8; ++k)
            a[k] += __shfl_down(a[k], off, 64);
    if (lane < 8) {
        float inv = (e > s) ? 1.0f / (float)(e - s) : 1.0f;
        union { __half2 h[4]; float4 f; } u;
        u.h[0] = __floats2half2_rn(a[0] * inv, a[1] * inv);
        u.h[1] = __floats2half2_rn(a[2] * inv, a[3] * inv);
        u.h[2] = __floats2half2_rn(a[4] * inv, a[5] * inv);
        u.h[3] = __floats2half2_rn(a[6] * inv, a[7] * inv);
        *(float4*)(AGGH + (size_t)node * CH + sub * 8) = u.f;
    }
}

// ---- shared GEMM staging: As[k][n] from fp16 A-table + fp16 AGG ----
__device__ __forceinline__ void gemm_stage(const __half* __restrict__ A,
                                           const __half* __restrict__ AGGH,
                                           const float* __restrict__ W,
                                           float (*As)[68], float (*Ws)[68],
                                           int t, int base, int N) {
    {
        int o = t >> 2;
        int k0 = (t & 3) * 32;
        const float4* wr = (const float4*)(W + o * 128 + k0);
#pragma unroll
        for (int q = 0; q < 8; ++q) {
            float4 v = wr[q];
            Ws[k0 + q * 4 + 0][o] = v.x;
            Ws[k0 + q * 4 + 1][o] = v.y;
            Ws[k0 + q * 4 + 2][o] = v.z;
            Ws[k0 + q * 4 + 3][o] = v.w;
        }
    }
    {
        int n = t >> 2;
        int c0 = (t & 3) * 16;
        int gn = base + n;
        if (gn < N) {
            const float4* xr = (const float4*)(A + (size_t)gn * CH + c0);
            const float4* gr = (const float4*)(AGGH + (size_t)gn * CH + c0);
#pragma unroll
            for (int q = 0; q < 2; ++q) {
                union { float4 f; __half2 h[4]; } u;
                u.f = xr[q];
#pragma unroll
                for (int p = 0; p < 4; ++p) {
                    As[c0 + q * 8 + 2 * p + 0][n] = __low2float(u.h[p]);
                    As[c0 + q * 8 + 2 * p + 1][n] = __high2float(u.h[p]);
                }
                union { float4 f; __half2 h[4]; } g;
                g.f = gr[q];
#pragma unroll
                for (int p = 0; p < 4; ++p) {
                    As[64 + c0 + q * 8 + 2 * p + 0][n] = __low2float(g.h[p]);
                    As[64 + c0 + q * 8 + 2 * p + 1][n] = __high2float(g.h[p]);
                }
            }
        } else {
#pragma unroll
            for (int i = 0; i < 16; ++i) {
                As[c0 + i][n] = 0.f;
                As[64 + c0 + i][n] = 0.f;
            }
        }
    }
}

// ---- layer-1/2 GEMM core producing acc[4][4] ----
#define GEMM_CORE(As, Ws, acc, n0, o0)                                          \
    _Pragma("unroll 4")                                                          \
    for (int k = 0; k < 128; ++k) {                                              \
        float4 a = *(const float4*)&As[k][n0];                                   \
        float4 w = *(const float4*)&Ws[k][o0];                                   \
        acc[0][0] += a.x * w.x; acc[0][1] += a.x * w.y; acc[0][2] += a.x * w.z; acc[0][3] += a.x * w.w; \
        acc[1][0] += a.y * w.x; acc[1][1] += a.y * w.y; acc[1][2] += a.y * w.z; acc[1][3] += a.y * w.w; \
        acc[2][0] += a.z * w.x; acc[2][1] += a.z * w.y; acc[2][2] += a.z * w.z; acc[2][3] += a.z * w.w; \
        acc[3][0] += a.w * w.x; acc[3][1] += a.w * w.y; acc[3][2] += a.w * w.z; acc[3][3] += a.w * w.w; \
    }

// ---- layer-1: h1 = relu(cat(xh,agg).W1^T + b1), fp16 out ----
__global__ __launch_bounds__(256) void k_gemm(const __half* __restrict__ A,
                                              const __half* __restrict__ AGGH,
                                              const float* __restrict__ W,
                                              const float* __restrict__ bias,
                                              __half* __restrict__ OUT, int N) {
    __shared__ float As[128][68];
    __shared__ float Ws[128][68];
    int t = threadIdx.x;
    int base = blockIdx.x * 64;
    gemm_stage(A, AGGH, W, As, Ws, t, base, N);
    __syncthreads();
    int o0 = (t & 15) * 4;
    int n0 = (t >> 4) * 4;
    float acc[4][4];
#pragma unroll
    for (int i = 0; i < 4; ++i)
#pragma unroll
        for (int jj = 0; jj < 4; ++jj) acc[i][jj] = 0.f;
    GEMM_CORE(As, Ws, acc, n0, o0);
    float4 bv = *(const float4*)&bias[o0];
#pragma unroll
    for (int i = 0; i < 4; ++i) {
        int gn = base + n0 + i;
        if (gn < N) {
            float rx = fmaxf(acc[i][0] + bv.x, 0.f);
            float ry = fmaxf(acc[i][1] + bv.y, 0.f);
            float rz = fmaxf(acc[i][2] + bv.z, 0.f);
            float rw = fmaxf(acc[i][3] + bv.w, 0.f);
            union { __half2 h[2]; float2 f; } u;
            u.h[0] = __floats2half2_rn(rx, ry);
            u.h[1] = __floats2half2_rn(rz, rw);
            *(float2*)(OUT + (size_t)gn * CH + o0) = u.f;
        }
    }
}

// ---- layer-2 + layer-3 dots: t[n]=relu(h2).W3[0:64], s[n]=relu(h2).W3[64:128] ----
__global__ __launch_bounds__(256) void k_gemm2(const __half* __restrict__ A,
                                               const __half* __restrict__ AGGH,
                                               const float* __restrict__ W,
                                               const float* __restrict__ bias,
                                               const float* __restrict__ W3,
                                               float* __restrict__ tarr,
                                               float* __restrict__ sarr, int N) {
    __shared__ float As[128][68];
    __shared__ float Ws[128][68];
    int t = threadIdx.x;
    int base = blockIdx.x * 64;
    gemm_stage(A, AGGH, W, As, Ws, t, base, N);
    __syncthreads();
    int o0 = (t & 15) * 4;
    int n0 = (t >> 4) * 4;
    float acc[4][4];
#pragma unroll
    for (int i = 0; i < 4; ++i)
#pragma unroll
        for (int jj = 0; jj < 4; ++jj) acc[i][jj] = 0.f;
    GEMM_CORE(As, Ws, acc, n0, o0);
    float4 bv  = *(const float4*)&bias[o0];
    float4 w3s = *(const float4*)&W3[o0];
    float4 w3a = *(const float4*)&W3[64 + o0];
#pragma unroll
    for (int i = 0; i < 4; ++i) {
        float rx = fmaxf(acc[i][0] + bv.x, 0.f);
        float ry = fmaxf(acc[i][1] + bv.y, 0.f);
        float rz = fmaxf(acc[i][2] + bv.z, 0.f);
        float rw = fmaxf(acc[i][3] + bv.w, 0.f);
        float tp = rx * w3s.x + ry * w3s.y + rz * w3s.z + rw * w3s.w;
        float sp = rx * w3a.x + ry * w3a.y + rz * w3a.z + rw * w3a.w;
#pragma unroll
        for (int off = 8; off >= 1; off >>= 1) {
            tp += __shfl_down(tp, off, 16);
            sp += __shfl_down(sp, off, 16);
        }
        int gn = base + n0 + i;
        if ((t & 15) == 0 && gn < N) {
            tarr[gn] = tp;
            sarr[gn] = sp;
        }
    }
}

// ---- Final: out[n] = t[n] + mean_j s[col_j] + b3 (4B/edge gather) ----
__global__ __launch_bounds__(256) void k_fin(const float* __restrict__ tarr,
                                             const float* __restrict__ sarr,
                                             const int* __restrict__ offs,
                                             const int* __restrict__ scol,
                                             const float* __restrict__ b3,
                                             float* __restrict__ out, int N) {
    int n = blockIdx.x * 256 + threadIdx.x;
    if (n >= N) return;
    int s = offs[n], e = offs[n + 1];
    float s0 = 0.f, s1 = 0.f, s2 = 0.f, s3 = 0.f;
    int j = s;
    for (; j + 4 <= e; j += 4) {
        s0 += sarr[scol[j]];
        s1 += sarr[scol[j + 1]];
        s2 += sarr[scol[j + 2]];
        s3 += sarr[scol[j + 3]];
    }
    for (; j < e; ++j) s0 += sarr[scol[j]];
    float inv = (e > s) ? 1.0f / (float)(e - s) : 1.0f;
    out[n] = tarr[n] + ((s0 + s1) + (s2 + s3)) * inv + b3[0];
}

extern "C" void kernel_launch(void* const* d_in, const int* in_sizes, int n_in,
                              void* d_out, int out_size, void* d_ws, size_t ws_size,
                              hipStream_t stream) {
    const float* x   = (const float*)d_in[0];
    const int* eidx  = (const int*)d_in[1];
    const float* W1  = (const float*)d_in[2];
    const float* b1  = (const float*)d_in[3];
    const float* W2  = (const float*)d_in[4];
    const float* b2  = (const float*)d_in[5];
    const float* W3  = (const float*)d_in[6];
    const float* b3  = (const float*)d_in[7];
    float* out = (float*)d_out;

    const int N = in_sizes[0] / CH;
    const int E = in_sizes[1] / 2;
    const int* row = eidx;
    const int* col = eidx + E;

    int offs_sz = ((N + 1 + 3) / 4) * 4;
    int e_sz    = ((E + 3) / 4) * 4;
    size_t tbl  = (size_t)(N + 1) * CH;  // halves per table (incl. zero row)

    int* offs    = (int*)d_ws;                      // offs_sz ints
    int* scol    = offs + offs_sz;                  // e_sz ints
    __half* xh   = (__half*)(scol + e_sz);          // tbl halves
    __half* h1   = xh + tbl;                        // tbl halves
    __half* aggh = h1 + tbl;                        // N*CH halves
    float* tarr  = (float*)(aggh + (size_t)N * CH); // N floats
    float* sarr  = tarr + N;                        // N floats
    // sort scratch aliases aggh region (dead before aggh's first write)
    int* ebuf   = (int*)aggh;                       // E ints
    int nbk     = (N + BKT_ROWS - 1) >> BKT_SHIFT;
    int* hist   = ebuf + e_sz;                      // nbk*NBLK
    int* histsc = hist + (size_t)nbk * NBLK;        // nbk*NBLK
    int* part   = histsc + (size_t)nbk * NBLK;      // scan partials

    int M = nbk * NBLK;
    int per_blk = (E + NBLK - 1) / NBLK;
    int mb = (M + 1023) / 1024;
    int abl = (N + 3) / 4;
    int gbl = (N + 63) / 64;
    int cvb = (N * CH / 4 + 255) / 256;

    // CSR build
    k_hist<<<NBLK, 256, 0, stream>>>(row, hist, E, nbk, per_blk);
    k_ssum<<<mb, 256, 0, stream>>>(hist, part, M);
    k_sser<<<1, 64, 0, stream>>>(part, mb);
    k_sscan<<<mb, 256, 0, stream>>>(hist, part, histsc, M);
    k_binscatter<<<NBLK, 256, 0, stream>>>(row, col, histsc, ebuf, E, nbk, per_blk);
    k_build<<<nbk, 256, 0, stream>>>(histsc, ebuf, offs, scol, N, E, nbk);

    // x -> fp16 table (+ zero dummy rows of xh, h1)
    k_tohalf<<<cvb, 256, 0, stream>>>(x, xh, h1, N * CH, N);

    // layer 1
    k_agg<<<abl, 256, 0, stream>>>((const float4*)xh, offs, scol, aggh, N, E - 1);
    k_gemm<<<gbl, 256, 0, stream>>>(xh, aggh, W1, b1, h1, N);
    // layer 2 (+ fused layer-3 dots)
    k_agg<<<abl, 256, 0, stream>>>((const float4*)h1, offs, scol, aggh, N, E - 1);
    k_gemm2<<<gbl, 256, 0, stream>>>(h1, aggh, W2, b2, W3, tarr, sarr, N);
    // layer 3 finish
    k_fin<<<(N + 255) / 256, 256, 0, stream>>>(tarr, sarr, offs, scol, b3, out, N);
}